// Round 6
// baseline (214.518 us; speedup 1.0000x reference)
//
#include <hip/hip_runtime.h>
#include <hip/hip_bf16.h>

// ---------------------------------------------------------------------------
// SingleLayerMoE: T=1024 tokens, H=1024, E=8 experts, I=1024, top-2 routing.
// R5: LDS double-buffer K-loop (ONE barrier per 64-k), PF2 register distance
//     (chunk i+3 loaded at iter i), down reverted to streaming dout + combine
//     (R4's 8.4M atomicAdds suspected ~60us), hipMemsetAsync for counts.
// ---------------------------------------------------------------------------

typedef unsigned short u16;
typedef __attribute__((ext_vector_type(8))) __bf16 bf16x8;
typedef __attribute__((ext_vector_type(4))) float f32x4;

#define T_TOK 1024
#define H_DIM 1024
#define E_NUM 8
#define I_DIM 1024
#define ALPHA 1.702f
#define LIMIT 7.0f
#define LSTR 72                 // u16 row stride; staging writes & b128 frag reads 2-way = free
#define AROWS 2112              // act/dout rows incl slack
#define DPART (AROWS * 1024)    // floats per K-split partial

__device__ __forceinline__ u16 f2bf(float f) {
    unsigned u = __builtin_bit_cast(unsigned, f);
    u = (u + 0x7FFFu + ((u >> 16) & 1u)) >> 16;
    return (u16)u;
}

__device__ __forceinline__ unsigned pk2(float lo, float hi) {
#if defined(__has_builtin) && __has_builtin(__builtin_amdgcn_cvt_pk_bf16_f32)
    typedef __attribute__((ext_vector_type(2))) __bf16 bf16x2_t;
    bf16x2_t v = __builtin_amdgcn_cvt_pk_bf16_f32(lo, hi);
    return __builtin_bit_cast(unsigned, v);
#else
    return (unsigned)f2bf(lo) | ((unsigned)f2bf(hi) << 16);
#endif
}

__device__ __forceinline__ f32x4 mfma16(bf16x8 a, bf16x8 b, f32x4 c) {
    return __builtin_amdgcn_mfma_f32_16x16x32_bf16(a, b, c, 0, 0, 0);
}

__device__ __forceinline__ void expert_range(const int* counts, int e,
                                             int& cnt, int& abase) {
    int a = 0, c = 0;
#pragma unroll
    for (int i = 0; i < E_NUM; ++i) {
        int v = counts[i];
        if (i < e) a += v;
        if (i == e) c = v;
    }
    cnt = c; abase = a;
}

// ------------- K1: router + dispatch + x->bf16 ------------------------------
__global__ __launch_bounds__(256) void k_router(
    const float* __restrict__ x, const float* __restrict__ rw,
    const float* __restrict__ rb,
    int* __restrict__ counts, int* __restrict__ tk_e, int* __restrict__ tk_slot,
    float* __restrict__ tk_w, int* __restrict__ tok_list,
    float* __restrict__ w_list, u16* __restrict__ xb)
{
    const int t = blockIdx.x;
    const int tid = threadIdx.x;
    const float4 xv = *(const float4*)(x + (size_t)t * H_DIM + tid * 4);

    *(uint2*)(xb + (size_t)t * H_DIM + tid * 4) =
        make_uint2(pk2(xv.x, xv.y), pk2(xv.z, xv.w));

    float p[E_NUM];
#pragma unroll
    for (int e = 0; e < E_NUM; ++e) {
        const float4 wv = *(const float4*)(rw + e * H_DIM + tid * 4);
        p[e] = xv.x * wv.x + xv.y * wv.y + xv.z * wv.z + xv.w * wv.w;
    }
#pragma unroll
    for (int off = 32; off; off >>= 1) {
#pragma unroll
        for (int e = 0; e < E_NUM; ++e) p[e] += __shfl_down(p[e], off, 64);
    }
    __shared__ float red[4][E_NUM];
    const int lane = tid & 63, wvid = tid >> 6;
    if (lane == 0) {
#pragma unroll
        for (int e = 0; e < E_NUM; ++e) red[wvid][e] = p[e];
    }
    __syncthreads();
    if (tid == 0) {
        float lg[E_NUM];
#pragma unroll
        for (int e = 0; e < E_NUM; ++e)
            lg[e] = red[0][e] + red[1][e] + red[2][e] + red[3][e] + rb[e];
        float m1 = -1e30f, m2 = -1e30f; int i1 = 0, i2 = 0;
#pragma unroll
        for (int e = 0; e < E_NUM; ++e) {
            float l = lg[e];
            if (l > m1) { m2 = m1; i2 = i1; m1 = l; i1 = e; }
            else if (l > m2) { m2 = l; i2 = e; }
        }
        float s = 0.f;
#pragma unroll
        for (int e = 0; e < E_NUM; ++e) s += __expf(lg[e] - m1);
        const float w0 = 1.0f / s;
        const float w1 = __expf(m2 - m1) / s;
        int ee[2] = { i1, i2 };
        float ww[2] = { w0, w1 };
#pragma unroll
        for (int k = 0; k < 2; ++k) {
            int e = ee[k];
            int slot = atomicAdd(&counts[e], 1);
            tok_list[e * T_TOK + slot] = t;
            w_list[e * T_TOK + slot] = ww[k];
            tk_e[t * 2 + k] = e;
            tk_slot[t * 2 + k] = slot;
            tk_w[t * 2 + k] = ww[k];
        }
    }
}

// --------------------------- K2: gate_up GEMM + GLU -------------------------
// tile 64 rows x (32 gate + 32 up), 64-k steps, LDS dbuf (1 barrier/step),
// PF2 reg distance; grid (32 strips, 16 m, 8 e).
__global__ __launch_bounds__(256) void k_gateup(
    const float* __restrict__ gup, const float* __restrict__ gub,
    const int* __restrict__ counts, const int* __restrict__ tok_list,
    const u16* __restrict__ xb, u16* __restrict__ act)
{
    const int e = blockIdx.z;
    int cnt, abase;
    expert_range(counts, e, cnt, abase);
    const int m0 = blockIdx.y * 64;
    if (m0 >= cnt) return;
    const int n0 = blockIdx.x * 32;
    const int tid = threadIdx.x;

    __shared__ __align__(16) u16 As[2][64 * LSTR];   // 2 x 9.2 KB
    __shared__ __align__(16) u16 Bs[2][64 * LSTR];   // rows 0..31 gate, 32..63 up
    
    const int arow_i = tid >> 2, akq = (tid & 3) * 16;
    const int aslot = m0 + arow_i;
    const int atok = (aslot < cnt) ? tok_list[e * T_TOK + aslot] : 0;
    const u16* asrc = xb + (size_t)atok * H_DIM + akq;
    const int aoff = arow_i * LSTR + akq;

    const int kp = tid >> 3, q = tid & 7;            // k-pair 2kp,2kp+1; col quad
    const float* bgate = gup + ((size_t)e << 21) + n0 + q * 4;

    const int lane = tid & 63, wv = tid >> 6;
    const int fm = lane & 15, kg = lane >> 4;

    f32x4 accg[2], accu[2];
#pragma unroll
    for (int nt = 0; nt < 2; ++nt) {
        accg[nt] = (f32x4){0.f, 0.f, 0.f, 0.f};
        accu[nt] = (f32x4){0.f, 0.f, 0.f, 0.f};
    }

#define GU_LOAD(A0, A1, G0, G1, U0, U1, CH)                                    \
    {                                                                          \
        const u16* ap_ = asrc + (CH) * 64;                                     \
        A0 = *(const uint4*)(ap_);                                             \
        A1 = *(const uint4*)(ap_ + 8);                                         \
        const float* gp_ = bgate + (size_t)((CH) * 64 + 2 * kp) * 2048;        \
        G0 = *(const float4*)(gp_);                                            \
        G1 = *(const float4*)(gp_ + 2048);                                     \
        U0 = *(const float4*)(gp_ + 1024);                                     \
        U1 = *(const float4*)(gp_ + 3072);                                     \
    }
#define GU_STORE(BUF, A0, A1, G0, G1, U0, U1)                                  \
    {                                                                          \
        *(uint4*)&As[BUF][aoff]     = A0;                                      \
        *(uint4*)&As[BUF][aoff + 8] = A1;                                      \
        unsigned* b32_ = (unsigned*)&Bs[BUF][0];                               \
        const float* g0_ = (const float*)&G0; const float* g1_ = (const float*)&G1; \
        const float* u0_ = (const float*)&U0; const float* u1_ = (const float*)&U1; \
        _Pragma("unroll")                                                      \
        for (int j = 0; j < 4; ++j) {                                          \
            b32_[(q * 4 + j) * 36 + kp]      = pk2(g0_[j], g1_[j]);            \
            b32_[(32 + q * 4 + j) * 36 + kp] = pk2(u0_[j], u1_[j]);            \
        }                                                                      \
    }
#define GU_MFMA(BUF)                                                           \
    {                                                                          \
        _Pragma("unroll")                                                      \
        for (int sub = 0; sub < 2; ++sub) {                                    \
            bf16x8 af = *(const bf16x8*)&As[BUF][(wv * 16 + fm) * LSTR + sub * 32 + kg * 8]; \
            _Pragma("unroll")                                                  \
            for (int nt = 0; nt < 2; ++nt) {                                   \
                bf16x8 bg = *(const bf16x8*)&Bs[BUF][(nt * 16 + fm) * LSTR + sub * 32 + kg * 8]; \
                bf16x8 bu = *(const bf16x8*)&Bs[BUF][(32 + nt * 16 + fm) * LSTR + sub * 32 + kg * 8]; \
                accg[nt] = mfma16(af, bg, accg[nt]);                           \
                accu[nt] = mfma16(af, bu, accu[nt]);                           \
            }                                                                  \
        }                                                                      \
    }

    // 16 chunks of 64-k. regs R0/R1; LDS buf ping-pong; ONE barrier per chunk.
    uint4 a0r0, a1r0, a0r1, a1r1;
    float4 g0r0, g1r0, u0r0, u1r0, g0r1, g1r1, u0r1, u1r1;
    GU_LOAD(a0r0, a1r0, g0r0, g1r0, u0r0, u1r0, 0);
    GU_LOAD(a0r1, a1r1, g0r1, g1r1, u0r1, u1r1, 1);
    GU_STORE(0, a0r0, a1r0, g0r0, g1r0, u0r0, u1r0);
    GU_LOAD(a0r0, a1r0, g0r0, g1r0, u0r0, u1r0, 2);

#pragma unroll 4
    for (int i = 0; i < 16; ++i) {
        __syncthreads();
        const int b = i & 1;
        if (i < 15) {
            if (b == 0) { GU_STORE(1, a0r1, a1r1, g0r1, g1r1, u0r1, u1r1); }
            else        { GU_STORE(0, a0r0, a1r0, g0r0, g1r0, u0r0, u1r0); }
        }
        if (i < 13) {
            if (b == 0) { GU_LOAD(a0r1, a1r1, g0r1, g1r1, u0r1, u1r1, i + 3); }
            else        { GU_LOAD(a0r0, a1r0, g0r0, g1r0, u0r0, u1r0, i + 3); }
        }
        GU_MFMA(b);
    }
#undef GU_LOAD
#undef GU_STORE
#undef GU_MFMA

#pragma unroll
    for (int r = 0; r < 4; ++r) {
        int rowb = wv * 16 + kg * 4 + r;       // C/D: row=(lane>>4)*4+reg
        int slot = m0 + rowb;
        if (slot >= cnt) continue;
        size_t arow_o = (size_t)(abase + slot) * I_DIM;
#pragma unroll
        for (int nt = 0; nt < 2; ++nt) {
            int cn = n0 + nt * 16 + fm;        // C/D: col=lane&15
            float g = accg[nt][r] + gub[e * 2048 + cn];
            float u = accu[nt][r] + gub[e * 2048 + 1024 + cn];
            g = fminf(g, LIMIT);
            u = fminf(fmaxf(u, -LIMIT), LIMIT);
            float glu = g / (1.f + __expf(-ALPHA * g));
            act[arow_o + cn] = f2bf((u + 1.f) * glu);
        }
    }
}

// ------------- K3: down GEMM * w -> streaming dout (K-split 2) --------------
// tile 64 rows x 64 cols, 64-k steps, LDS dbuf, PF2; grid (16,16,8e*2ks).
__global__ __launch_bounds__(256) void k_down(
    const float* __restrict__ dp,
    const int* __restrict__ counts, const float* __restrict__ w_list,
    const u16* __restrict__ act, float* __restrict__ dout)
{
    const int e = blockIdx.z & 7, ks = blockIdx.z >> 3;
    int cnt, abase;
    expert_range(counts, e, cnt, abase);
    const int m0 = blockIdx.y * 64;
    if (m0 >= cnt) return;
    const int n0 = blockIdx.x * 64;
    const int tid = threadIdx.x;

    __shared__ __align__(16) u16 As[2][64 * LSTR];
    __shared__ __align__(16) u16 Bs[2][64 * LSTR];

    const int arow_i = tid >> 2, akq = (tid & 3) * 16;
    const u16* asrc = act + (size_t)(abase + m0 + arow_i) * I_DIM + ks * 512 + akq;
    const int aoff = arow_i * LSTR + akq;

    const int kp = tid >> 3, q = tid & 7;
    const float* bsrc = dp + ((size_t)e << 20) + (size_t)(ks * 512) * 1024 + n0 + q * 4;

    const int lane = tid & 63, wv = tid >> 6;
    const int fm = lane & 15, kg = lane >> 4;

    f32x4 acc[4];
#pragma unroll
    for (int nt = 0; nt < 4; ++nt) acc[nt] = (f32x4){0.f, 0.f, 0.f, 0.f};

#define DN_LOAD(A0, A1, B00, B01, B10, B11, CH)                                \
    {                                                                          \
        const u16* ap_ = asrc + (CH) * 64;                                     \
        A0 = *(const uint4*)(ap_);                                             \
        A1 = *(const uint4*)(ap_ + 8);                                         \
        const float* bp_ = bsrc + (size_t)((CH) * 64 + 2 * kp) * 1024;         \
        B00 = *(const float4*)(bp_);                                           \
        B01 = *(const float4*)(bp_ + 1024);                                    \
        B10 = *(const float4*)(bp_ + 32);                                      \
        B11 = *(const float4*)(bp_ + 1056);                                    \
    }
#define DN_STORE(BUF, A0, A1, B00, B01, B10, B11)                              \
    {                                                                          \
        *(uint4*)&As[BUF][aoff]     = A0;                                      \
        *(uint4*)&As[BUF][aoff + 8] = A1;                                      \
        unsigned* b32_ = (unsigned*)&Bs[BUF][0];                               \
        const float* b00_ = (const float*)&B00; const float* b01_ = (const float*)&B01; \
        const float* b10_ = (const float*)&B10; const float* b11_ = (const float*)&B11; \
        _Pragma("unroll")                                                      \
        for (int j = 0; j < 4; ++j) {                                          \
            b32_[(q * 4 + j) * 36 + kp]      = pk2(b00_[j], b01_[j]);          \
            b32_[(32 + q * 4 + j) * 36 + kp] = pk2(b10_[j], b11_[j]);          \
        }                                                                      \
    }
#define DN_MFMA(BUF)                                                           \
    {                                                                          \
        _Pragma("unroll")                                                      \
        for (int sub = 0; sub < 2; ++sub) {                                    \
            bf16x8 af = *(const bf16x8*)&As[BUF][(wv * 16 + fm) * LSTR + sub * 32 + kg * 8]; \
            _Pragma("unroll")                                                  \
            for (int nt = 0; nt < 4; ++nt) {                                   \
                bf16x8 bb = *(const bf16x8*)&Bs[BUF][(nt * 16 + fm) * LSTR + sub * 32 + kg * 8]; \
                acc[nt] = mfma16(af, bb, acc[nt]);                             \
            }                                                                  \
        }                                                                      \
    }

    uint4 a0r0, a1r0, a0r1, a1r1;
    float4 b00r0, b01r0, b10r0, b11r0, b00r1, b01r1, b10r1, b11r1;
    DN_LOAD(a0r0, a1r0, b00r0, b01r0, b10r0, b11r0, 0);
    DN_LOAD(a0r1, a1r1, b00r1, b01r1, b10r1, b11r1, 1);
    DN_STORE(0, a0r0, a1r0, b00r0, b01r0, b10r0, b11r0);
    DN_LOAD(a0r0, a1r0, b00r0, b01r0, b10r0, b11r0, 2);

#pragma unroll 4
    for (int i = 0; i < 8; ++i) {
        __syncthreads();
        const int b = i & 1;
        if (i < 7) {
            if (b == 0) { DN_STORE(1, a0r1, a1r1, b00r1, b01r1, b10r1, b11r1); }
            else        { DN_STORE(0, a0r0, a1r0, b00r0, b01r0, b10r0, b11r0); }
        }
        if (i < 5) {
            if (b == 0) { DN_LOAD(a0r1, a1r1, b00r1, b01r1, b10r1, b11r1, i + 3); }
            else        { DN_LOAD(a0r0, a1r0, b00r0, b01r0, b10r0, b11r0, i + 3); }
        }
        DN_MFMA(b);
    }
#undef DN_LOAD
#undef DN_STORE
#undef DN_MFMA

#pragma unroll
    for (int r = 0; r < 4; ++r) {
        int rowb = wv * 16 + kg * 4 + r;
        int slot = m0 + rowb;
        if (slot >= cnt) continue;
        float wgt = w_list[e * T_TOK + slot];
        size_t drow = (size_t)ks * DPART + (size_t)(abase + slot) * H_DIM;
#pragma unroll
        for (int nt = 0; nt < 4; ++nt)
            dout[drow + n0 + nt * 16 + fm] = acc[nt][r] * wgt;
    }
}

// --------------------------- K4: combine ------------------------------------
__global__ __launch_bounds__(256) void k_combine(
    const float* __restrict__ dout, const float* __restrict__ db,
    const int* __restrict__ counts,
    const int* __restrict__ tk_e, const int* __restrict__ tk_slot,
    const float* __restrict__ tk_w, float* __restrict__ out)
{
    const int t = blockIdx.x, tid = threadIdx.x;
    const int e0 = tk_e[t * 2], e1 = tk_e[t * 2 + 1];
    int c0, a0base, c1, a1base;
    expert_range(counts, e0, c0, a0base);
    expert_range(counts, e1, c1, a1base);
    const size_t p0 = (size_t)(a0base + tk_slot[t * 2]) * H_DIM;
    const size_t p1 = (size_t)(a1base + tk_slot[t * 2 + 1]) * H_DIM;
    const float w0 = tk_w[t * 2], w1 = tk_w[t * 2 + 1];
    const int c = tid * 4;
    float4 x0 = *(const float4*)(dout + p0 + c);
    float4 x1 = *(const float4*)(dout + DPART + p0 + c);
    float4 y0 = *(const float4*)(dout + p1 + c);
    float4 y1 = *(const float4*)(dout + DPART + p1 + c);
    float4 d0 = *(const float4*)(db + e0 * H_DIM + c);
    float4 d1 = *(const float4*)(db + e1 * H_DIM + c);
    float4 o;
    o.x = x0.x + x1.x + y0.x + y1.x + w0 * d0.x + w1 * d1.x;
    o.y = x0.y + x1.y + y0.y + y1.y + w0 * d0.y + w1 * d1.y;
    o.z = x0.z + x1.z + y0.z + y1.z + w0 * d0.z + w1 * d1.z;
    o.w = x0.w + x1.w + y0.w + y1.w + w0 * d0.w + w1 * d1.w;
    *(float4*)(out + (size_t)t * H_DIM + c) = o;
}

// ---------------------------------------------------------------------------
extern "C" void kernel_launch(void* const* d_in, const int* in_sizes, int n_in,
                              void* d_out, int out_size, void* d_ws, size_t ws_size,
                              hipStream_t stream) {
    const float* x   = (const float*)d_in[0]; // [1,1024,1024]
    const float* rw  = (const float*)d_in[1]; // [8,1024]
    const float* rb  = (const float*)d_in[2]; // [8]
    const float* gup = (const float*)d_in[3]; // [8,1024,2048]
    const float* gub = (const float*)d_in[4]; // [8,2048]
    const float* dp  = (const float*)d_in[5]; // [8,1024,1024]
    const float* db  = (const float*)d_in[6]; // [8,1024]
    float* out = (float*)d_out;

    char* ws = (char*)d_ws;
    int*   counts   = (int*)(ws);               // 64 B
    int*   tk_e     = (int*)(ws + 64);          // 8 KB
    int*   tk_slot  = (int*)(ws + 8256);        // 8 KB
    float* tk_w     = (float*)(ws + 16448);     // 8 KB
    int*   tok_list = (int*)(ws + 24640);       // 32 KB
    float* w_list   = (float*)(ws + 57408);     // 32 KB
    u16*   xb       = (u16*)(ws + 90176);       // 2 MB
    u16*   act      = (u16*)(ws + 90176 + 2097152);          // 2112*1024 bf16
    float* dout     = (float*)(ws + 90176 + 2097152 + 4325376); // 2 x 2112*1024 f32

    hipMemsetAsync(counts, 0, 64, stream);
    k_router<<<T_TOK, 256, 0, stream>>>(x, rw, rb, counts, tk_e, tk_slot, tk_w,
                                        tok_list, w_list, xb);
    k_gateup<<<dim3(32, 16, 8), 256, 0, stream>>>(gup, gub, counts, tok_list,
                                                  xb, act);
    k_down<<<dim3(16, 16, 16), 256, 0, stream>>>(dp, counts, w_list, act, dout);
    k_combine<<<T_TOK, 256, 0, stream>>>(dout, db, counts, tk_e, tk_slot, tk_w,
                                         out);
}